// Round 1
// baseline (577.449 us; speedup 1.0000x reference)
//
#include <hip/hip_runtime.h>
#include <stdint.h>

#define NN 32768
#define DEG 16
#define CH 128
#define G4 512
#define MB 32          // nodes per LSTM block

typedef short bf16x8 __attribute__((ext_vector_type(8)));
typedef float f32x4 __attribute__((ext_vector_type(4)));
typedef unsigned short u16;
typedef u16 u16x8 __attribute__((ext_vector_type(8)));

__device__ __forceinline__ u16 f2bf(float f) {
  union { float f; uint32_t u; } v; v.f = f;
  uint32_t u = v.u;
  return (u16)((u + 0x7FFFu + ((u >> 16) & 1u)) >> 16);
}
__device__ __forceinline__ float sigm(float x) { return 1.0f / (1.0f + __expf(-x)); }
__device__ __forceinline__ float tanh_f(float x) { return 1.0f - 2.0f / (1.0f + __expf(2.0f * x)); }

// swizzled LDS address: row stride 512B, XOR row into byte bits 4..6
__device__ __forceinline__ u16* swz(u16* base, int row, int col) {
  int b = (row * 256 + col) * 2;
  b ^= (row & 7) << 4;
  return (u16*)((char*)base + b);
}

// ---------------- prep kernels ----------------
__global__ void k_cvt_bf16(const float* __restrict__ in, u16* __restrict__ out, int n8) {
  int i = blockIdx.x * blockDim.x + threadIdx.x;
  if (i >= n8) return;
  const float* pp = in + (size_t)i * 8;
  u16x8 o;
  #pragma unroll
  for (int j = 0; j < 8; ++j) o[j] = f2bf(pp[j]);
  *(u16x8*)(out + (size_t)i * 8) = o;
}

__global__ void k_pack_lstm(const float* __restrict__ wih, const float* __restrict__ whh,
                            const float* __restrict__ bih, const float* __restrict__ bhh,
                            u16* __restrict__ Wc, float* __restrict__ bs) {
  int idx = blockIdx.x * blockDim.x + threadIdx.x;   // 512*256
  int g = idx >> 8, k = idx & 255;
  float v = (k < CH) ? wih[g * CH + k] : whh[g * CH + (k - CH)];
  Wc[g * 256 + k] = f2bf(v);
  if (k == 0) bs[g] = bih[g] + bhh[g];
}

__global__ void k_pack_lin(const float* __restrict__ wl, const float* __restrict__ wr,
                           u16* __restrict__ W) {
  int idx = blockIdx.x * blockDim.x + threadIdx.x;   // 128*256
  int o = idx >> 8, k = idx & 255;
  float v = (k < CH) ? wl[o * CH + k] : wr[o * CH + (k - CH)];
  W[o * 256 + k] = f2bf(v);
}

// ---------------- LSTM aggregation ----------------
// block: 512 threads = 8 waves, 32 nodes. wave w owns channels [w*16, w*16+16)
// of all 4 gates; weights register-resident; [x_t | h] staged in swizzled LDS.
__global__ __launch_bounds__(512, 2)
void k_lstm(const u16* __restrict__ xin, const int* __restrict__ src,
            const u16* __restrict__ Wc, const float* __restrict__ bs,
            u16* __restrict__ aggr) {
  __shared__ u16 xh[MB * 256];       // 16 KB, swizzled
  __shared__ int srcs[MB * DEG];     // 2 KB
  const int tid = threadIdx.x;
  const int lane = tid & 63;
  const int wave = tid >> 6;
  const int l15 = lane & 15;
  const int lg  = lane >> 4;
  const int nodeBase = blockIdx.x * MB;

  srcs[tid] = src[nodeBase * DEG + tid];

  // B-fragments: Wf[gate][ktile], row = gate*128 + wave*16 + l15
  bf16x8 Wf[4][8];
  {
    const u16* wp = Wc + (wave * 16 + l15) * 256 + lg * 8;
    #pragma unroll
    for (int gt = 0; gt < 4; ++gt)
      #pragma unroll
      for (int kt = 0; kt < 8; ++kt)
        Wf[gt][kt] = *(const bf16x8*)(wp + gt * (CH * 256) + kt * 32);
  }
  float bias[4];
  #pragma unroll
  for (int gt = 0; gt < 4; ++gt) bias[gt] = bs[gt * CH + wave * 16 + l15];

  const int r  = tid >> 4;          // staging row 0..31
  const int cc = (tid & 15) * 8;    // staging col chunk

  __syncthreads();                  // srcs visible

  { // stage x_0, zero h-region
    int s = srcs[r * DEG];
    bf16x8 v = *(const bf16x8*)(xin + (size_t)s * CH + cc);
    *(bf16x8*)swz(xh, r, cc) = v;
    bf16x8 z = {};
    *(bf16x8*)swz(xh, r, CH + cc) = z;
  }

  f32x4 cst[2] = {};
  u16 hb[2][4];

  for (int t = 0; t < DEG; ++t) {
    __syncthreads();                // xh staged (x_t and h_{t-1})
    // prefetch next neighbor row into regs (hides L2 latency under MFMA)
    bf16x8 xpre = {};
    if (t + 1 < DEG) {
      int s = srcs[r * DEG + t + 1];
      xpre = *(const bf16x8*)(xin + (size_t)s * CH + cc);
    }
    f32x4 acc[2][4];
    #pragma unroll
    for (int mt = 0; mt < 2; ++mt) {
      bf16x8 A[8];
      #pragma unroll
      for (int kt = 0; kt < 8; ++kt)
        A[kt] = *(const bf16x8*)swz(xh, mt * 16 + l15, kt * 32 + lg * 8);
      #pragma unroll
      for (int gt = 0; gt < 4; ++gt) {
        f32x4 a = { bias[gt], bias[gt], bias[gt], bias[gt] };
        #pragma unroll
        for (int kt = 0; kt < 8; ++kt)
          a = __builtin_amdgcn_mfma_f32_16x16x32_bf16(A[kt], Wf[gt][kt], a, 0, 0, 0);
        acc[mt][gt] = a;
      }
    }
    // elementwise LSTM cell update (f32), c stays in regs
    #pragma unroll
    for (int mt = 0; mt < 2; ++mt) {
      #pragma unroll
      for (int q = 0; q < 4; ++q) {
        float iv = sigm(acc[mt][0][q]);
        float fv = sigm(acc[mt][1][q]);
        float gv = tanh_f(acc[mt][2][q]);
        float ov = sigm(acc[mt][3][q]);
        float c  = fv * cst[mt][q] + iv * gv;
        cst[mt][q] = c;
        hb[mt][q] = f2bf(ov * tanh_f(c));
      }
    }
    __syncthreads();                // all xh reads done
    if (t + 1 < DEG) {
      // write h_t (C/D layout: row=(lg*4+q), col=l15)
      #pragma unroll
      for (int mt = 0; mt < 2; ++mt)
        #pragma unroll
        for (int q = 0; q < 4; ++q)
          *swz(xh, mt * 16 + lg * 4 + q, CH + wave * 16 + l15) = hb[mt][q];
      // stage x_{t+1}
      *(bf16x8*)swz(xh, r, cc) = xpre;
    }
  }

  // write aggr = h_15 (bf16) from registers
  #pragma unroll
  for (int mt = 0; mt < 2; ++mt)
    #pragma unroll
    for (int q = 0; q < 4; ++q)
      aggr[(size_t)(nodeBase + mt * 16 + lg * 4 + q) * CH + wave * 16 + l15] = hb[mt][q];
}

// ---------------- fused lin_l/lin_r ----------------
// out[n] = aggr[n] @ wl.T + bl + xroot[n] @ wr.T ; optional relu + bf16 out
__global__ __launch_bounds__(256, 4)
void k_linear(const u16* __restrict__ aggr, const u16* __restrict__ xroot,
              const u16* __restrict__ W, const float* __restrict__ bl,
              u16* __restrict__ out_bf, float* __restrict__ out_f, int relu) {
  const int lane = threadIdx.x & 63;
  const int wave = threadIdx.x >> 6;
  const int l15 = lane & 15, lg = lane >> 4;
  const int rowBase = blockIdx.x * 64 + wave * 16;

  f32x4 acc[8];
  #pragma unroll
  for (int nt = 0; nt < 8; ++nt) {
    float b = bl[nt * 16 + l15];
    acc[nt] = { b, b, b, b };
  }
  #pragma unroll
  for (int kt = 0; kt < 8; ++kt) {
    const u16* ap = (kt < 4) ? (aggr  + (size_t)(rowBase + l15) * CH + kt * 32 + lg * 8)
                             : (xroot + (size_t)(rowBase + l15) * CH + (kt - 4) * 32 + lg * 8);
    bf16x8 A = *(const bf16x8*)ap;
    #pragma unroll
    for (int nt = 0; nt < 8; ++nt) {
      bf16x8 B = *(const bf16x8*)(W + (nt * 16 + l15) * 256 + kt * 32 + lg * 8);
      acc[nt] = __builtin_amdgcn_mfma_f32_16x16x32_bf16(A, B, acc[nt], 0, 0, 0);
    }
  }
  #pragma unroll
  for (int nt = 0; nt < 8; ++nt) {
    #pragma unroll
    for (int q = 0; q < 4; ++q) {
      float v = acc[nt][q];
      if (relu) v = fmaxf(v, 0.0f);
      int row = rowBase + lg * 4 + q;
      int col = nt * 16 + l15;
      if (out_bf) out_bf[(size_t)row * CH + col] = f2bf(v);
      else        out_f[(size_t)row * CH + col]  = v;
    }
  }
}

extern "C" void kernel_launch(void* const* d_in, const int* in_sizes, int n_in,
                              void* d_out, int out_size, void* d_ws, size_t ws_size,
                              hipStream_t stream) {
  (void)in_sizes; (void)n_in; (void)out_size; (void)ws_size;
  const float* x    = (const float*)d_in[0];
  const int*   ei   = (const int*)d_in[1];   // row 0 = src (dst-sorted, fixed degree)
  const float* w1ih = (const float*)d_in[2];
  const float* w1hh = (const float*)d_in[3];
  const float* b1ih = (const float*)d_in[4];
  const float* b1hh = (const float*)d_in[5];
  const float* w1l  = (const float*)d_in[6];
  const float* b1l  = (const float*)d_in[7];
  const float* w1r  = (const float*)d_in[8];
  const float* w2ih = (const float*)d_in[9];
  const float* w2hh = (const float*)d_in[10];
  const float* b2ih = (const float*)d_in[11];
  const float* b2hh = (const float*)d_in[12];
  const float* w2l  = (const float*)d_in[13];
  const float* b2l  = (const float*)d_in[14];
  const float* w2r  = (const float*)d_in[15];

  char* p = (char*)d_ws;
  u16* x_bf  = (u16*)p;  p += (size_t)NN * CH * 2;
  u16* h1_bf = (u16*)p;  p += (size_t)NN * CH * 2;
  u16* ag_bf = (u16*)p;  p += (size_t)NN * CH * 2;
  u16* Wc1   = (u16*)p;  p += G4 * 256 * 2;
  u16* Wc2   = (u16*)p;  p += G4 * 256 * 2;
  u16* Wl1   = (u16*)p;  p += CH * 256 * 2;
  u16* Wl2   = (u16*)p;  p += CH * 256 * 2;
  float* bs1 = (float*)p; p += G4 * 4;
  float* bs2 = (float*)p; p += G4 * 4;

  k_cvt_bf16<<<(NN * CH / 8 + 255) / 256, 256, 0, stream>>>(x, x_bf, NN * CH / 8);
  k_pack_lstm<<<G4, 256, 0, stream>>>(w1ih, w1hh, b1ih, b1hh, Wc1, bs1);
  k_pack_lstm<<<G4, 256, 0, stream>>>(w2ih, w2hh, b2ih, b2hh, Wc2, bs2);
  k_pack_lin<<<CH, 256, 0, stream>>>(w1l, w1r, Wl1);
  k_pack_lin<<<CH, 256, 0, stream>>>(w2l, w2r, Wl2);

  k_lstm<<<NN / MB, 512, 0, stream>>>(x_bf, ei, Wc1, bs1, ag_bf);
  k_linear<<<NN / 64, 256, 0, stream>>>(ag_bf, x_bf, Wl1, b1l, h1_bf, nullptr, 1);
  k_lstm<<<NN / MB, 512, 0, stream>>>(h1_bf, ei, Wc2, bs2, ag_bf);
  k_linear<<<NN / 64, 256, 0, stream>>>(ag_bf, h1_bf, Wl2, b2l, nullptr, (float*)d_out, 0);
}

// Round 2
// 319.148 us; speedup vs baseline: 1.8093x; 1.8093x over previous
//
#include <hip/hip_runtime.h>
#include <stdint.h>

#define NN 32768
#define DEG 16
#define CH 128
#define G4 512
#define MB 64          // nodes per LSTM block

typedef short bf16x8 __attribute__((ext_vector_type(8)));
typedef float f32x4 __attribute__((ext_vector_type(4)));
typedef unsigned short u16;
typedef u16 u16x8 __attribute__((ext_vector_type(8)));
typedef uint32_t u32;

#define L2E 1.4426950408889634f

__device__ __forceinline__ u16 f2bf(float f) {
  union { float f; uint32_t u; } v; v.f = f;
  uint32_t u = v.u;
  return (u16)((u + 0x7FFFu + ((u >> 16) & 1u)) >> 16);
}

__device__ __forceinline__ float exp2f_fast(float x) {
#if __has_builtin(__builtin_amdgcn_exp2f)
  return __builtin_amdgcn_exp2f(x);
#else
  float r; asm("v_exp_f32 %0, %1" : "=v"(r) : "v"(x)); return r;
#endif
}
__device__ __forceinline__ float rcpf_fast(float x) {
#if __has_builtin(__builtin_amdgcn_rcpf)
  return __builtin_amdgcn_rcpf(x);
#else
  float r; asm("v_rcp_f32 %0, %1" : "=v"(r) : "v"(x)); return r;
#endif
}
__device__ __forceinline__ u32 cvtpk(float lo, float hi) {
  u32 r; asm("v_cvt_pk_bf16_f32 %0, %1, %2" : "=v"(r) : "v"(lo), "v"(hi));
  return r;
}

// ---------------- prep kernels ----------------
__global__ void k_cvt_bf16(const float* __restrict__ in, u16* __restrict__ out, int n8) {
  int i = blockIdx.x * blockDim.x + threadIdx.x;
  if (i >= n8) return;
  const float* pp = in + (size_t)i * 8;
  u16x8 o;
  #pragma unroll
  for (int j = 0; j < 8; ++j) o[j] = f2bf(pp[j]);
  *(u16x8*)(out + (size_t)i * 8) = o;
}

// weights pre-scaled by log2e (2*log2e for gate g); bias negated for i,f,o
__global__ void k_pack_lstm(const float* __restrict__ wih, const float* __restrict__ whh,
                            const float* __restrict__ bih, const float* __restrict__ bhh,
                            u16* __restrict__ Wc, float* __restrict__ bs) {
  int idx = blockIdx.x * blockDim.x + threadIdx.x;   // 512*256
  int g = idx >> 8, k = idx & 255;
  int gate = g >> 7;
  float sc = (gate == 2) ? (2.0f * L2E) : L2E;
  float v = (k < CH) ? wih[g * CH + k] : whh[g * CH + (k - CH)];
  Wc[g * 256 + k] = f2bf(v * sc);
  if (k == 0) {
    float b = (bih[g] + bhh[g]) * sc;
    bs[g] = (gate == 2) ? b : -b;
  }
}

__global__ void k_pack_lin(const float* __restrict__ wl, const float* __restrict__ wr,
                           u16* __restrict__ W) {
  int idx = blockIdx.x * blockDim.x + threadIdx.x;   // 128*256
  int o = idx >> 8, k = idx & 255;
  float v = (k < CH) ? wl[o * CH + k] : wr[o * CH + (k - CH)];
  W[o * 256 + k] = f2bf(v);
}

// ---------------- LSTM aggregation ----------------
// 512 threads = 8 waves, 64 nodes/block. Wave w owns channels [w*16,w*16+16)
// of all 4 gates (cell update stays lane-local). Weights register-resident
// (ideally AGPR); [x_t | h] in swizzled LDS; all addresses hoisted.
__global__ __launch_bounds__(512, 2)
void k_lstm(const u16* __restrict__ xin, const int* __restrict__ src,
            const u16* __restrict__ Wc, const float* __restrict__ bs,
            u16* __restrict__ aggr) {
  __shared__ u16 xh[MB * 256];       // 32 KB, swizzled: byte = row*512 + (colb ^ ((row&7)<<4))
  __shared__ int srcs[MB * DEG];     // 4 KB
  const int tid = threadIdx.x;
  const int lane = tid & 63;
  const int wave = tid >> 6;
  const int l15 = lane & 15;
  const int lg  = lane >> 4;
  const int nodeBase = blockIdx.x * MB;

  srcs[tid]       = src[nodeBase * DEG + tid];
  srcs[tid + 512] = src[nodeBase * DEG + tid + 512];

  // B-fragments (scaled weights): row = gate*128 + wave*16 + l15
  bf16x8 Wf[4][8];
  {
    const u16* wp = Wc + (wave * 16 + l15) * 256 + lg * 8;
    #pragma unroll
    for (int gt = 0; gt < 4; ++gt)
      #pragma unroll
      for (int kt = 0; kt < 8; ++kt)
        Wf[gt][kt] = *(const bf16x8*)(wp + gt * (CH * 256) + kt * 32);
  }
  const float bi = bs[0 * CH + wave * 16 + l15];
  const float bf = bs[1 * CH + wave * 16 + l15];
  const float bg = bs[2 * CH + wave * 16 + l15];
  const float bo = bs[3 * CH + wave * 16 + l15];

  // hoisted addresses
  const int s_swz = (l15 & 7) << 4;
  int abase[4];
  #pragma unroll
  for (int mt = 0; mt < 4; ++mt)
    abase[mt] = (mt * 16 + l15) * 512 + ((lg * 16) ^ s_swz);   // ^ (kt*64) per read
  int haddr[4];
  #pragma unroll
  for (int q = 0; q < 4; ++q)
    haddr[q] = (lg * 4 + q) * 512 +
               ((256 + wave * 32 + l15 * 2) ^ ((((lg & 1) * 4) + q) << 4)); // + mt*8192
  const int r  = tid >> 4;                       // staging row 0..31 (and +32)
  const int ck = (tid & 15) << 4;                // byte chunk within row
  const int stg  = r * 512 + (ck ^ ((r & 7) << 4));
  const int stgH = r * 512 + ((256 + ck) ^ ((r & 7) << 4));
  const int sidx = r * DEG;

  __syncthreads();                  // srcs visible
  {                                 // stage x_0, zero h-region
    int s0 = srcs[sidx];
    int s1 = srcs[sidx + 32 * DEG];
    bf16x8 v0 = *(const bf16x8*)(xin + (size_t)s0 * CH + (ck >> 1));
    bf16x8 v1 = *(const bf16x8*)(xin + (size_t)s1 * CH + (ck >> 1));
    *(bf16x8*)((char*)xh + stg)          = v0;
    *(bf16x8*)((char*)xh + stg + 16384)  = v1;
    bf16x8 z = {};
    *(bf16x8*)((char*)xh + stgH)         = z;
    *(bf16x8*)((char*)xh + stgH + 16384) = z;
  }

  float cst[4][4] = {{0.f}};
  u32 hp[4][2];
  const f32x4 zero4 = {0.f, 0.f, 0.f, 0.f};

  #pragma unroll 1
  for (int t = 0; t < DEG; ++t) {
    __syncthreads();                // xh staged for step t
    bf16x8 xp0 = {}, xp1 = {};
    if (t + 1 < DEG) {              // prefetch next gather under compute
      int s0 = srcs[sidx + t + 1];
      int s1 = srcs[sidx + 32 * DEG + t + 1];
      xp0 = *(const bf16x8*)(xin + (size_t)s0 * CH + (ck >> 1));
      xp1 = *(const bf16x8*)(xin + (size_t)s1 * CH + (ck >> 1));
    }
    f32x4 acc[2][4];
    #pragma unroll
    for (int mt = 0; mt < 4; ++mt) {
      const int pp = mt & 1;        // ping-pong: elementwise(mt) ∥ MFMA(mt+1)
      #pragma unroll
      for (int kt = 0; kt < 8; ++kt) {
        bf16x8 A = *(const bf16x8*)((char*)xh + (abase[mt] ^ (kt * 64)));
        if (kt == 0) {
          #pragma unroll
          for (int gt = 0; gt < 4; ++gt)
            acc[pp][gt] = __builtin_amdgcn_mfma_f32_16x16x32_bf16(A, Wf[gt][0], zero4, 0, 0, 0);
        } else {
          #pragma unroll
          for (int gt = 0; gt < 4; ++gt)
            acc[pp][gt] = __builtin_amdgcn_mfma_f32_16x16x32_bf16(A, Wf[gt][kt], acc[pp][gt], 0, 0, 0);
        }
      }
      float hq[4];
      #pragma unroll
      for (int q = 0; q < 4; ++q) {
        // weights pre-scaled: sigm = rcp(1+exp2(nb - y)), tanh = 1-2*rcp(1+exp2(y+b))
        float si = rcpf_fast(1.0f + exp2f_fast(bi - acc[pp][0][q]));
        float sf = rcpf_fast(1.0f + exp2f_fast(bf - acc[pp][1][q]));
        float so = rcpf_fast(1.0f + exp2f_fast(bo - acc[pp][3][q]));
        float gg = fmaf(-2.0f, rcpf_fast(1.0f + exp2f_fast(acc[pp][2][q] + bg)), 1.0f);
        float c  = fmaf(sf, cst[mt][q], si * gg);
        cst[mt][q] = c;
        float tc = fmaf(-2.0f, rcpf_fast(1.0f + exp2f_fast(c * 2.8853900817779268f)), 1.0f);
        hq[q] = so * tc;
      }
      hp[mt][0] = cvtpk(hq[0], hq[1]);
      hp[mt][1] = cvtpk(hq[2], hq[3]);
    }
    __syncthreads();                // all xh reads done
    if (t + 1 < DEG) {
      #pragma unroll
      for (int mt = 0; mt < 4; ++mt) {
        *(u16*)((char*)xh + haddr[0] + mt * 8192) = (u16)(hp[mt][0]);
        *(u16*)((char*)xh + haddr[1] + mt * 8192) = (u16)(hp[mt][0] >> 16);
        *(u16*)((char*)xh + haddr[2] + mt * 8192) = (u16)(hp[mt][1]);
        *(u16*)((char*)xh + haddr[3] + mt * 8192) = (u16)(hp[mt][1] >> 16);
      }
      *(bf16x8*)((char*)xh + stg)         = xp0;
      *(bf16x8*)((char*)xh + stg + 16384) = xp1;
    }
  }

  // aggr = h_15 (bf16); C/D layout: row = lg*4+q, col = l15
  #pragma unroll
  for (int mt = 0; mt < 4; ++mt) {
    size_t rowb = (size_t)(nodeBase + mt * 16 + lg * 4);
    u16* op = aggr + rowb * CH + wave * 16 + l15;
    op[0 * CH] = (u16)(hp[mt][0]);
    op[1 * CH] = (u16)(hp[mt][0] >> 16);
    op[2 * CH] = (u16)(hp[mt][1]);
    op[3 * CH] = (u16)(hp[mt][1] >> 16);
  }
}

// ---------------- fused lin_l/lin_r ----------------
__global__ __launch_bounds__(256, 4)
void k_linear(const u16* __restrict__ aggr, const u16* __restrict__ xroot,
              const u16* __restrict__ W, const float* __restrict__ bl,
              u16* __restrict__ out_bf, float* __restrict__ out_f, int relu) {
  const int lane = threadIdx.x & 63;
  const int wave = threadIdx.x >> 6;
  const int l15 = lane & 15, lg = lane >> 4;
  const int rowBase = blockIdx.x * 64 + wave * 16;

  f32x4 acc[8];
  #pragma unroll
  for (int nt = 0; nt < 8; ++nt) {
    float b = bl[nt * 16 + l15];
    acc[nt] = { b, b, b, b };
  }
  #pragma unroll
  for (int kt = 0; kt < 8; ++kt) {
    const u16* ap = (kt < 4) ? (aggr  + (size_t)(rowBase + l15) * CH + kt * 32 + lg * 8)
                             : (xroot + (size_t)(rowBase + l15) * CH + (kt - 4) * 32 + lg * 8);
    bf16x8 A = *(const bf16x8*)ap;
    #pragma unroll
    for (int nt = 0; nt < 8; ++nt) {
      bf16x8 B = *(const bf16x8*)(W + (nt * 16 + l15) * 256 + kt * 32 + lg * 8);
      acc[nt] = __builtin_amdgcn_mfma_f32_16x16x32_bf16(A, B, acc[nt], 0, 0, 0);
    }
  }
  #pragma unroll
  for (int nt = 0; nt < 8; ++nt) {
    #pragma unroll
    for (int q = 0; q < 4; ++q) {
      float v = acc[nt][q];
      if (relu) v = fmaxf(v, 0.0f);
      int row = rowBase + lg * 4 + q;
      int col = nt * 16 + l15;
      if (out_bf) out_bf[(size_t)row * CH + col] = f2bf(v);
      else        out_f[(size_t)row * CH + col]  = v;
    }
  }
}

extern "C" void kernel_launch(void* const* d_in, const int* in_sizes, int n_in,
                              void* d_out, int out_size, void* d_ws, size_t ws_size,
                              hipStream_t stream) {
  (void)in_sizes; (void)n_in; (void)out_size; (void)ws_size;
  const float* x    = (const float*)d_in[0];
  const int*   ei   = (const int*)d_in[1];
  const float* w1ih = (const float*)d_in[2];
  const float* w1hh = (const float*)d_in[3];
  const float* b1ih = (const float*)d_in[4];
  const float* b1hh = (const float*)d_in[5];
  const float* w1l  = (const float*)d_in[6];
  const float* b1l  = (const float*)d_in[7];
  const float* w1r  = (const float*)d_in[8];
  const float* w2ih = (const float*)d_in[9];
  const float* w2hh = (const float*)d_in[10];
  const float* b2ih = (const float*)d_in[11];
  const float* b2hh = (const float*)d_in[12];
  const float* w2l  = (const float*)d_in[13];
  const float* b2l  = (const float*)d_in[14];
  const float* w2r  = (const float*)d_in[15];

  char* p = (char*)d_ws;
  u16* x_bf  = (u16*)p;  p += (size_t)NN * CH * 2;
  u16* h1_bf = (u16*)p;  p += (size_t)NN * CH * 2;
  u16* ag_bf = (u16*)p;  p += (size_t)NN * CH * 2;
  u16* Wc1   = (u16*)p;  p += G4 * 256 * 2;
  u16* Wc2   = (u16*)p;  p += G4 * 256 * 2;
  u16* Wl1   = (u16*)p;  p += CH * 256 * 2;
  u16* Wl2   = (u16*)p;  p += CH * 256 * 2;
  float* bs1 = (float*)p; p += G4 * 4;
  float* bs2 = (float*)p; p += G4 * 4;

  k_cvt_bf16<<<(NN * CH / 8 + 255) / 256, 256, 0, stream>>>(x, x_bf, NN * CH / 8);
  k_pack_lstm<<<G4, 256, 0, stream>>>(w1ih, w1hh, b1ih, b1hh, Wc1, bs1);
  k_pack_lstm<<<G4, 256, 0, stream>>>(w2ih, w2hh, b2ih, b2hh, Wc2, bs2);
  k_pack_lin<<<CH, 256, 0, stream>>>(w1l, w1r, Wl1);
  k_pack_lin<<<CH, 256, 0, stream>>>(w2l, w2r, Wl2);

  k_lstm<<<NN / MB, 512, 0, stream>>>(x_bf, ei, Wc1, bs1, ag_bf);
  k_linear<<<NN / 64, 256, 0, stream>>>(ag_bf, x_bf, Wl1, b1l, h1_bf, nullptr, 1);
  k_lstm<<<NN / MB, 512, 0, stream>>>(h1_bf, ei, Wc2, bs2, ag_bf);
  k_linear<<<NN / 64, 256, 0, stream>>>(ag_bf, h1_bf, Wl2, b2l, nullptr, (float*)d_out, 0);
}